// Round 1
// baseline (624.589 us; speedup 1.0000x reference)
//
#include <hip/hip_runtime.h>

#define T_TOTAL 4194304
#define LBLK 256
#define WARM 2048
#define NCHAIN (T_TOTAL / LBLK)   // 16384 chains -> 64 blocks x 256 threads

// ---------------- Kernel 1: variance of y via double-precision reduction ---------------
__global__ __launch_bounds__(256) void var_reduce(const float* __restrict__ y,
                                                  double* __restrict__ acc) {
    __shared__ double s_sum[4], s_sq[4];
    int tid = blockIdx.x * blockDim.x + threadIdx.x;
    int stride = gridDim.x * blockDim.x;
    double s = 0.0, q = 0.0;
    for (int i = tid; i < T_TOTAL; i += stride) {
        double v = (double)y[i];
        s += v;
        q += v * v;
    }
    for (int off = 32; off > 0; off >>= 1) {
        s += __shfl_down(s, off, 64);
        q += __shfl_down(q, off, 64);
    }
    int lane = threadIdx.x & 63, wid = threadIdx.x >> 6;
    if (lane == 0) { s_sum[wid] = s; s_sq[wid] = q; }
    __syncthreads();
    if (threadIdx.x == 0) {
        double ts = s_sum[0] + s_sum[1] + s_sum[2] + s_sum[3];
        double tq = s_sq[0] + s_sq[1] + s_sq[2] + s_sq[3];
        atomicAdd(&acc[0], ts);
        atomicAdd(&acc[1], tq);
    }
}

// ---------------- Kernel 2: blocked-in-time scan with contraction warm-up --------------
__global__ __launch_bounds__(256) void scan_blocks(
    const float* __restrict__ y, const float* __restrict__ rv,
    const float* __restrict__ Wi, const float* __restrict__ Ui, const float* __restrict__ bi,
    const float* __restrict__ Wf, const float* __restrict__ Uf, const float* __restrict__ bf,
    const float* __restrict__ Wo, const float* __restrict__ Uo, const float* __restrict__ bo,
    const float* __restrict__ Wc, const float* __restrict__ Uc, const float* __restrict__ bc,
    const float* __restrict__ p_omega, const float* __restrict__ p_alpha,
    const float* __restrict__ p_phi, const float* __restrict__ p_lam,
    const float* __restrict__ p_gam,
    const double* __restrict__ acc, float* __restrict__ out) {

    const int k = blockIdx.x * blockDim.x + threadIdx.x;  // chain id
    if (k >= NCHAIN) return;

    const float L2E = 1.44269504088896340736f;
    const float TWO_L2E = 2.88539008177792681472f;
    const float LN2 = 0.69314718055994530942f;

    // gate constants, pre-scaled so the chain needs no extra multiplies
    const float nA_i = -L2E * (Wi[0] + Ui[0]);
    const float nBy_i = -L2E * Wi[1], nBr_i = -L2E * Wi[2], nBz_i = -L2E * Wi[3];
    const float nb_i = -L2E * bi[0];
    const float nA_f = -L2E * (Wf[0] + Uf[0]);
    const float nBy_f = -L2E * Wf[1], nBr_f = -L2E * Wf[2], nBz_f = -L2E * Wf[3];
    const float nb_f = -L2E * bf[0];
    const float nA_o = -L2E * (Wo[0] + Uo[0]);
    const float nBy_o = -L2E * Wo[1], nBr_o = -L2E * Wo[2], nBz_o = -L2E * Wo[3];
    const float nb_o = -L2E * bo[0];
    const float tA_c = TWO_L2E * (Wc[0] + Uc[0]);
    const float tBy_c = TWO_L2E * Wc[1], tBr_c = TWO_L2E * Wc[2], tBz_c = TWO_L2E * Wc[3];
    const float tb_c = TWO_L2E * bc[0];

    const float omega = p_omega[0], alpha = p_alpha[0], phi = p_phi[0];
    const float lam = p_lam[0], gam = p_gam[0];
    const float C0 = omega * (1.0f - phi) - alpha;   // fold "- alpha*1"
    const float nag2 = -2.0f * alpha * gam;

    const double dsum = acc[0], dsq = acc[1];
    const float var =
        (float)((dsq - dsum * dsum / (double)T_TOTAL) / (double)T_TOTAL);

    int s0 = k * LBLK - WARM;
    if (s0 < 0) s0 = 0;
    const int wStart = k * LBLK;
    int sEnd = (k + 1) * LBLK;
    if (sEnd > T_TOTAL - 1) sEnd = T_TOTAL - 1;

    // carry init: exact for k==0; in-basin guess otherwise (warm-up contracts it)
    float eta = var, c = 0.0f, h = var;
    float z = fmaf(-lam, eta, y[s0]) * __builtin_amdgcn_rsqf(eta);

    if (k == 0) {
        out[0] = z;            // z_val[0] = z0
        out[T_TOTAL] = h;      // h_val[0] = var(y)
    }

#define STEP(YS, RS, YN, SIDX)                                                        \
    do {                                                                              \
        float bi_ = fmaf(nBy_i, (YS), fmaf(nBr_i, (RS), nb_i));                       \
        float bf_ = fmaf(nBy_f, (YS), fmaf(nBr_f, (RS), nb_f));                       \
        float bo_ = fmaf(nBy_o, (YS), fmaf(nBr_o, (RS), nb_o));                       \
        float bc_ = fmaf(tBy_c, (YS), fmaf(tBr_c, (RS), tb_c));                       \
        float pi_ = fmaf(nA_i, eta, fmaf(nBz_i, z, bi_));                             \
        float pf_ = fmaf(nA_f, eta, fmaf(nBz_f, z, bf_));                             \
        float po_ = fmaf(nA_o, eta, fmaf(nBz_o, z, bo_));                             \
        float pc_ = fmaf(tA_c, eta, fmaf(tBz_c, z, bc_));                             \
        float it_ = __builtin_amdgcn_rcpf(1.0f + __builtin_amdgcn_exp2f(pi_));        \
        float ft_ = __builtin_amdgcn_rcpf(1.0f + __builtin_amdgcn_exp2f(pf_));        \
        float ot_ = __builtin_amdgcn_rcpf(1.0f + __builtin_amdgcn_exp2f(po_));        \
        float gt_ = fmaf(-2.0f, __builtin_amdgcn_rcpf(1.0f + __builtin_amdgcn_exp2f(pc_)), 1.0f); \
        c = fmaf(ft_, c, it_ * gt_);                                                  \
        float th_ = fmaf(-2.0f,                                                       \
                         __builtin_amdgcn_rcpf(1.0f + __builtin_amdgcn_exp2f(c * TWO_L2E)), \
                         1.0f);                                                       \
        float u_ = ot_ * th_;                                                         \
        float sh_ = __builtin_amdgcn_sqrtf(h);                                        \
        float t1_ = fmaf(alpha, z * z, C0);                                           \
        h = fmaf(phi, h, fmaf(nag2 * z, sh_, t1_));                                   \
        eta = LN2 * __builtin_amdgcn_logf(1.0f + __builtin_amdgcn_exp2f(u_ * L2E));   \
        z = fmaf(-lam, eta, (YN)) * __builtin_amdgcn_rsqf(eta);                       \
        if ((SIDX) >= wStart) {                                                       \
            out[(SIDX) + 1] = z;                                                      \
            out[T_TOTAL + (SIDX) + 1] = h;                                            \
        }                                                                             \
    } while (0)

    const float4* __restrict__ y4 = reinterpret_cast<const float4*>(y);
    const float4* __restrict__ r4 = reinterpret_cast<const float4*>(rv);
    const int gmax = (T_TOTAL >> 2) - 1;

    int g = s0 >> 2;                      // s0 is a multiple of 4
    float4 yc = y4[g], rc = r4[g];
    int g1 = (g + 1 < gmax) ? g + 1 : gmax;
    float4 yn = y4[g1], rn = r4[g1];

    int s = s0;
    while (s < sEnd) {
        int g2 = (g + 2 < gmax) ? g + 2 : gmax;
        float4 ynn = y4[g2], rnn = r4[g2];   // depth-2 prefetch, off the chain

        STEP(yc.x, rc.x, yc.y, s);
        if (s + 1 < sEnd) {
            STEP(yc.y, rc.y, yc.z, s + 1);
            if (s + 2 < sEnd) {
                STEP(yc.z, rc.z, yc.w, s + 2);
                if (s + 3 < sEnd) {
                    STEP(yc.w, rc.w, yn.x, s + 3);
                }
            }
        }
        s += 4;
        g += 1;
        yc = yn; rc = rn;
        yn = ynn; rn = rnn;
    }
#undef STEP
}

extern "C" void kernel_launch(void* const* d_in, const int* in_sizes, int n_in,
                              void* d_out, int out_size, void* d_ws, size_t ws_size,
                              hipStream_t stream) {
    const float* y  = (const float*)d_in[0];
    const float* rv = (const float*)d_in[1];
    const float* Wi = (const float*)d_in[2];
    const float* Ui = (const float*)d_in[3];
    const float* bi = (const float*)d_in[4];
    const float* Wf = (const float*)d_in[5];
    const float* Uf = (const float*)d_in[6];
    const float* bf = (const float*)d_in[7];
    const float* Wo = (const float*)d_in[8];
    const float* Uo = (const float*)d_in[9];
    const float* bo = (const float*)d_in[10];
    const float* Wc = (const float*)d_in[11];
    const float* Uc = (const float*)d_in[12];
    const float* bc = (const float*)d_in[13];
    const float* om = (const float*)d_in[14];
    const float* al = (const float*)d_in[15];
    const float* ph = (const float*)d_in[16];
    const float* la = (const float*)d_in[17];
    const float* ga = (const float*)d_in[18];
    float* out = (float*)d_out;
    double* acc = (double*)d_ws;

    hipMemsetAsync(acc, 0, 2 * sizeof(double), stream);
    var_reduce<<<1024, 256, 0, stream>>>(y, acc);
    scan_blocks<<<NCHAIN / 256, 256, 0, stream>>>(
        y, rv, Wi, Ui, bi, Wf, Uf, bf, Wo, Uo, bo, Wc, Uc, bc,
        om, al, ph, la, ga, acc, out);
}

// Round 2
// 280.011 us; speedup vs baseline: 2.2306x; 2.2306x over previous
//
#include <hip/hip_runtime.h>

#define T_TOTAL 4194304
#define LBLK 256
#define WARM1 768                      // warm-up length (multiple of 256 and 4)
#define NCHAIN (T_TOTAL / LBLK)        // 16384 chains
#define CPB 64                         // chains per block = 1 wave
#define GMAX ((T_TOTAL >> 2) - 1)

// ---------------- Kernel 1: variance of y (float4 loads, fp64 accum) ---------------
__global__ __launch_bounds__(256) void var_reduce(const float* __restrict__ y,
                                                  double* __restrict__ acc) {
    __shared__ double s_sum[4], s_sq[4];
    const float4* __restrict__ y4 = reinterpret_cast<const float4*>(y);
    int tid = blockIdx.x * 256 + threadIdx.x;
    const int nthr = 1024 * 256;
    double s = 0.0, q = 0.0;
    for (int i = tid; i < (T_TOTAL >> 2); i += nthr) {
        float4 v = y4[i];
        double a = v.x, b = v.y, c = v.z, d = v.w;
        s += (a + b) + (c + d);
        q += (a * a + b * b) + (c * c + d * d);
    }
    for (int off = 32; off > 0; off >>= 1) {
        s += __shfl_down(s, off, 64);
        q += __shfl_down(q, off, 64);
    }
    int lane = threadIdx.x & 63, wid = threadIdx.x >> 6;
    if (lane == 0) { s_sum[wid] = s; s_sq[wid] = q; }
    __syncthreads();
    if (threadIdx.x == 0) {
        double ts = s_sum[0] + s_sum[1] + s_sum[2] + s_sum[3];
        double tq = s_sq[0] + s_sq[1] + s_sq[2] + s_sq[3];
        atomicAdd(&acc[0], ts);
        atomicAdd(&acc[1], tq);
    }
}

// ---------------- Kernel 2: blocked-in-time scan, poly-softplus, LDS-staged out ----
__global__ __launch_bounds__(64) void scan_blocks(
    const float* __restrict__ y, const float* __restrict__ rv,
    const float* __restrict__ Wi, const float* __restrict__ Ui, const float* __restrict__ bi,
    const float* __restrict__ Wf, const float* __restrict__ Uf, const float* __restrict__ bf,
    const float* __restrict__ Wo, const float* __restrict__ Uo, const float* __restrict__ bo,
    const float* __restrict__ Wc, const float* __restrict__ Uc, const float* __restrict__ bc,
    const float* __restrict__ p_omega, const float* __restrict__ p_alpha,
    const float* __restrict__ p_phi, const float* __restrict__ p_lam,
    const float* __restrict__ p_gam,
    const double* __restrict__ acc, float* __restrict__ out) {

    __shared__ float zs[CPB * 17];
    __shared__ float hs[CPB * 17];

    const int k = blockIdx.x * CPB + threadIdx.x;   // chain id (owns out[256k..256k+256))

    const float L2E = 1.44269504088896340736f;
    const float TWO_L2E = 2.88539008177792681472f;
    const float LN2 = 0.69314718055994530942f;
    // lncosh(u/2) Taylor coeffs in w=u^2
    const float SPC1 = 0.125f;
    const float SPC2 = -5.2083333333e-3f;
    const float SPC3 = 3.4722222222e-4f;
    const float SPC4 = -2.6351897e-5f;

    const float nA_i = -L2E * (Wi[0] + Ui[0]);
    const float nBy_i = -L2E * Wi[1], nBr_i = -L2E * Wi[2], nBz_i = -L2E * Wi[3];
    const float nb_i = -L2E * bi[0];
    const float nA_f = -L2E * (Wf[0] + Uf[0]);
    const float nBy_f = -L2E * Wf[1], nBr_f = -L2E * Wf[2], nBz_f = -L2E * Wf[3];
    const float nb_f = -L2E * bf[0];
    const float nA_o = -L2E * (Wo[0] + Uo[0]);
    const float nBy_o = -L2E * Wo[1], nBr_o = -L2E * Wo[2], nBz_o = -L2E * Wo[3];
    const float nb_o = -L2E * bo[0];
    const float tA_c = TWO_L2E * (Wc[0] + Uc[0]);
    const float tBy_c = TWO_L2E * Wc[1], tBr_c = TWO_L2E * Wc[2], tBz_c = TWO_L2E * Wc[3];
    const float tb_c = TWO_L2E * bc[0];

    const float omega = p_omega[0], alpha = p_alpha[0], phi = p_phi[0];
    const float lam = p_lam[0], gam = p_gam[0];
    const float C0 = omega * (1.0f - phi) - alpha;
    const float nag2 = -2.0f * alpha * gam;

    const double dsum = acc[0], dsq = acc[1];
    const float var =
        (float)((dsq - dsum * dsum / (double)T_TOTAL) / (double)T_TOTAL);

    int sstart = k * LBLK - WARM1;
    if (sstart < 0) sstart = 0;
    const int send = k * LBLK;   // exclusive end of warm-up; output window starts here

    // carry init: EXACT for chains with sstart==0 (k<=3); in-basin guess otherwise
    float eta = var, c = 0.0f, h = var;
    float z = fmaf(-lam, eta, y[sstart]) * __builtin_amdgcn_rsqf(eta);

#define STEP(YS, RS, YN)                                                              \
    do {                                                                              \
        float bi_ = fmaf(nBy_i, (YS), fmaf(nBr_i, (RS), nb_i));                       \
        float bf_ = fmaf(nBy_f, (YS), fmaf(nBr_f, (RS), nb_f));                       \
        float bo_ = fmaf(nBy_o, (YS), fmaf(nBr_o, (RS), nb_o));                       \
        float bc_ = fmaf(tBy_c, (YS), fmaf(tBr_c, (RS), tb_c));                       \
        float pi_ = fmaf(nA_i, eta, fmaf(nBz_i, z, bi_));                             \
        float pf_ = fmaf(nA_f, eta, fmaf(nBz_f, z, bf_));                             \
        float po_ = fmaf(nA_o, eta, fmaf(nBz_o, z, bo_));                             \
        float pc_ = fmaf(tA_c, eta, fmaf(tBz_c, z, bc_));                             \
        float it_ = __builtin_amdgcn_rcpf(1.0f + __builtin_amdgcn_exp2f(pi_));        \
        float ft_ = __builtin_amdgcn_rcpf(1.0f + __builtin_amdgcn_exp2f(pf_));        \
        float ot_ = __builtin_amdgcn_rcpf(1.0f + __builtin_amdgcn_exp2f(po_));        \
        float gt_ = fmaf(-2.0f, __builtin_amdgcn_rcpf(1.0f + __builtin_amdgcn_exp2f(pc_)), 1.0f); \
        c = fmaf(ft_, c, it_ * gt_);                                                  \
        float th_ = fmaf(-2.0f,                                                       \
                         __builtin_amdgcn_rcpf(1.0f + __builtin_amdgcn_exp2f(c * TWO_L2E)), \
                         1.0f);                                                       \
        float u_ = ot_ * th_;                                                         \
        float sh_ = __builtin_amdgcn_sqrtf(h);                                        \
        float t1_ = fmaf(alpha, z * z, C0);                                           \
        h = fmaf(phi, h, fmaf(nag2 * z, sh_, t1_));                                   \
        float w_ = u_ * u_;                                                           \
        float pl_ = fmaf(w_, fmaf(w_, fmaf(w_, SPC4, SPC3), SPC2), SPC1);             \
        eta = fmaf(w_, pl_, fmaf(0.5f, u_, LN2));                                     \
        z = fmaf(-lam, eta, (YN)) * __builtin_amdgcn_rsqf(eta);                       \
    } while (0)

    const float4* __restrict__ y4 = reinterpret_cast<const float4*>(y);
    const float4* __restrict__ r4 = reinterpret_cast<const float4*>(rv);

    // ---------------- warm-up (no outputs; per-lane trip count, no barriers) -------
    {
        int g = sstart >> 2;
        int g1 = g + 1; if (g1 > GMAX) g1 = GMAX;
        float4 yc = y4[g], rc = r4[g];
        float4 yn = y4[g1], rn = r4[g1];
        for (int s = sstart; s < send; s += 4) {
            int g2 = g + 2; if (g2 > GMAX) g2 = GMAX;
            float4 ynn = y4[g2], rnn = r4[g2];
            STEP(yc.x, rc.x, yc.y);
            STEP(yc.y, rc.y, yc.z);
            STEP(yc.z, rc.z, yc.w);
            STEP(yc.w, rc.w, yn.x);
            g += 1;
            yc = yn; rc = rn;
            yn = ynn; rn = rnn;
        }
    }

    // ---------------- output phase: 256 steps, stage-then-step, LDS-chunked flush --
    {
        int g = send >> 2;
        float4 yc = y4[g], rc = r4[g];
        int g1 = g + 1; if (g1 > GMAX) g1 = GMAX;
        float4 yn = y4[g1], rn = r4[g1];
        const long ob4 = (long)blockIdx.x * (CPB * 64);  // block's out region in float4s
        float4* __restrict__ out4 = reinterpret_cast<float4*>(out);
        const int lb0 = threadIdx.x * 17;

        for (int mq = 0; mq < 64; ++mq) {
            int g2 = g + 2; if (g2 > GMAX) g2 = GMAX;
            float4 ynn = y4[g2], rnn = r4[g2];
            const int jj = (mq & 3) * 4;

            zs[lb0 + jj] = z;     hs[lb0 + jj] = h;
            STEP(yc.x, rc.x, yc.y);
            zs[lb0 + jj + 1] = z; hs[lb0 + jj + 1] = h;
            STEP(yc.y, rc.y, yc.z);
            zs[lb0 + jj + 2] = z; hs[lb0 + jj + 2] = h;
            STEP(yc.z, rc.z, yc.w);
            zs[lb0 + jj + 3] = z; hs[lb0 + jj + 3] = h;

            if ((mq & 3) == 3) {
                __syncthreads();
                const int j0q = (mq >> 2) << 2;       // chunk base in float4 units
#pragma unroll
                for (int ff = 0; ff < 4; ++ff) {
                    int F = ff * CPB + threadIdx.x;
                    int cc = F >> 2, q = F & 3;
                    int lb = cc * 17 + q * 4;
                    float4 zv = make_float4(zs[lb], zs[lb + 1], zs[lb + 2], zs[lb + 3]);
                    float4 hv = make_float4(hs[lb], hs[lb + 1], hs[lb + 2], hs[lb + 3]);
                    long o4 = ob4 + (long)cc * 64 + j0q + q;
                    out4[o4] = zv;
                    out4[(T_TOTAL >> 2) + o4] = hv;
                }
                __syncthreads();
            }

            STEP(yc.w, rc.w, yn.x);
            g += 1;
            yc = yn; rc = rn;
            yn = ynn; rn = rnn;
        }
    }
#undef STEP
}

extern "C" void kernel_launch(void* const* d_in, const int* in_sizes, int n_in,
                              void* d_out, int out_size, void* d_ws, size_t ws_size,
                              hipStream_t stream) {
    const float* y  = (const float*)d_in[0];
    const float* rv = (const float*)d_in[1];
    const float* Wi = (const float*)d_in[2];
    const float* Ui = (const float*)d_in[3];
    const float* bi = (const float*)d_in[4];
    const float* Wf = (const float*)d_in[5];
    const float* Uf = (const float*)d_in[6];
    const float* bf = (const float*)d_in[7];
    const float* Wo = (const float*)d_in[8];
    const float* Uo = (const float*)d_in[9];
    const float* bo = (const float*)d_in[10];
    const float* Wc = (const float*)d_in[11];
    const float* Uc = (const float*)d_in[12];
    const float* bc = (const float*)d_in[13];
    const float* om = (const float*)d_in[14];
    const float* al = (const float*)d_in[15];
    const float* ph = (const float*)d_in[16];
    const float* la = (const float*)d_in[17];
    const float* ga = (const float*)d_in[18];
    float* out = (float*)d_out;
    double* acc = (double*)d_ws;

    hipMemsetAsync(acc, 0, 2 * sizeof(double), stream);
    var_reduce<<<1024, 256, 0, stream>>>(y, acc);
    scan_blocks<<<NCHAIN / CPB, 64, 0, stream>>>(
        y, rv, Wi, Ui, bi, Wf, Uf, bf, Wo, Uo, bo, Wc, Uc, bc,
        om, al, ph, la, ga, acc, out);
}

// Round 6
// 193.399 us; speedup vs baseline: 3.2295x; 1.4478x over previous
//
#include <hip/hip_runtime.h>

#define T_TOTAL 4194304
#define LBLK 64                        // outputs per chain
#define WARM1 384                      // warm-up steps (multiple of 4)
#define NCHAIN (T_TOTAL / LBLK)        // 65536 chains
#define CPB 64                         // chains per block = 1 wave
#define NBLK (NCHAIN / CPB)            // 1024 blocks
#define VBLK 256                       // var_reduce blocks
#define GMAX ((T_TOTAL >> 2) - 1)

// ---------------- Kernel 1: variance partials (no atomics) ---------------
__global__ __launch_bounds__(256) void var_reduce(const float* __restrict__ y,
                                                  double* __restrict__ ws) {
    __shared__ double s_sum[4], s_sq[4];
    const float4* __restrict__ y4 = reinterpret_cast<const float4*>(y);
    int tid = blockIdx.x * 256 + threadIdx.x;
    const int nthr = VBLK * 256;
    double s = 0.0, q = 0.0;
    for (int i = tid; i < (T_TOTAL >> 2); i += nthr) {
        float4 v = y4[i];
        double a = v.x, b = v.y, c = v.z, d = v.w;
        s += (a + b) + (c + d);
        q += (a * a + b * b) + (c * c + d * d);
    }
    for (int off = 32; off > 0; off >>= 1) {
        s += __shfl_down(s, off, 64);
        q += __shfl_down(q, off, 64);
    }
    int lane = threadIdx.x & 63, wid = threadIdx.x >> 6;
    if (lane == 0) { s_sum[wid] = s; s_sq[wid] = q; }
    __syncthreads();
    if (threadIdx.x == 0) {
        ws[blockIdx.x] = s_sum[0] + s_sum[1] + s_sum[2] + s_sum[3];
        ws[VBLK + blockIdx.x] = s_sq[0] + s_sq[1] + s_sq[2] + s_sq[3];
    }
}

// ---------------- Kernel 2: blocked-in-time scan ----
__global__ __launch_bounds__(64) void scan_blocks(
    const float* __restrict__ y, const float* __restrict__ rv,
    const float* __restrict__ Wi, const float* __restrict__ Ui, const float* __restrict__ bi,
    const float* __restrict__ Wf, const float* __restrict__ Uf, const float* __restrict__ bf,
    const float* __restrict__ Wo, const float* __restrict__ Uo, const float* __restrict__ bo,
    const float* __restrict__ Wc, const float* __restrict__ Uc, const float* __restrict__ bc,
    const float* __restrict__ p_omega, const float* __restrict__ p_alpha,
    const float* __restrict__ p_phi, const float* __restrict__ p_lam,
    const float* __restrict__ p_gam,
    const double* __restrict__ ws, float* __restrict__ out) {

    __shared__ float zs[CPB * 65];
    __shared__ float hs[CPB * 65];

    const int t = threadIdx.x;
    const int k = blockIdx.x * CPB + t;   // chain id; owns out[64k .. 64k+64)

    // ---- reduce variance partials (1 wave, no barrier needed) ----
    double s = ws[t] + ws[t + 64] + ws[t + 128] + ws[t + 192];
    double q = ws[VBLK + t] + ws[VBLK + t + 64] + ws[VBLK + t + 128] + ws[VBLK + t + 192];
    for (int off = 32; off > 0; off >>= 1) {
        s += __shfl_down(s, off, 64);
        q += __shfl_down(q, off, 64);
    }
    s = __shfl(s, 0, 64);
    q = __shfl(q, 0, 64);
    const float var = (float)((q - s * s / (double)T_TOTAL) / (double)T_TOTAL);

    const float L2E = 1.44269504088896340736f;
    const float TWO_L2E = 2.88539008177792681472f;
    const float LN2 = 0.69314718055994530942f;
    const float SPC1 = 0.125f;
    const float SPC2 = -5.2083333333e-3f;
    const float SPC3 = 3.4722222222e-4f;
    const float SPC4 = -2.6351897e-5f;

    const float nA_i = -L2E * (Wi[0] + Ui[0]);
    const float nBy_i = -L2E * Wi[1], nBr_i = -L2E * Wi[2], nBz_i = -L2E * Wi[3];
    const float nb_i = -L2E * bi[0];
    const float nA_f = -L2E * (Wf[0] + Uf[0]);
    const float nBy_f = -L2E * Wf[1], nBr_f = -L2E * Wf[2], nBz_f = -L2E * Wf[3];
    const float nb_f = -L2E * bf[0];
    const float nA_o = -L2E * (Wo[0] + Uo[0]);
    const float nBy_o = -L2E * Wo[1], nBr_o = -L2E * Wo[2], nBz_o = -L2E * Wo[3];
    const float nb_o = -L2E * bo[0];
    const float tA_c = TWO_L2E * (Wc[0] + Uc[0]);
    const float tBy_c = TWO_L2E * Wc[1], tBr_c = TWO_L2E * Wc[2], tBz_c = TWO_L2E * Wc[3];
    const float tb_c = TWO_L2E * bc[0];

    const float omega = p_omega[0], alpha = p_alpha[0], phi = p_phi[0];
    const float lam = p_lam[0], gam = p_gam[0];
    const float C0 = omega * (1.0f - phi) - alpha;
    const float nag2 = -2.0f * alpha * gam;

    int sstart = k * LBLK - WARM1;
    if (sstart < 0) sstart = 0;
    const int send = k * LBLK;

    // carry init: EXACT for chains with sstart==0; in-basin guess otherwise
    float eta = var, c = 0.0f, h = var;
    float z = fmaf(-lam, eta, y[sstart]) * __builtin_amdgcn_rsqf(eta);

#define STEP(YS, RS, YN)                                                              \
    do {                                                                              \
        float bi_ = fmaf(nBy_i, (YS), fmaf(nBr_i, (RS), nb_i));                       \
        float bf_ = fmaf(nBy_f, (YS), fmaf(nBr_f, (RS), nb_f));                       \
        float bo_ = fmaf(nBy_o, (YS), fmaf(nBr_o, (RS), nb_o));                       \
        float bc_ = fmaf(tBy_c, (YS), fmaf(tBr_c, (RS), tb_c));                       \
        float pi_ = fmaf(nA_i, eta, fmaf(nBz_i, z, bi_));                             \
        float pf_ = fmaf(nA_f, eta, fmaf(nBz_f, z, bf_));                             \
        float po_ = fmaf(nA_o, eta, fmaf(nBz_o, z, bo_));                             \
        float pc_ = fmaf(tA_c, eta, fmaf(tBz_c, z, bc_));                             \
        float it_ = __builtin_amdgcn_rcpf(1.0f + __builtin_amdgcn_exp2f(pi_));        \
        float ft_ = __builtin_amdgcn_rcpf(1.0f + __builtin_amdgcn_exp2f(pf_));        \
        float ot_ = __builtin_amdgcn_rcpf(1.0f + __builtin_amdgcn_exp2f(po_));        \
        float gt_ = fmaf(-2.0f, __builtin_amdgcn_rcpf(1.0f + __builtin_amdgcn_exp2f(pc_)), 1.0f); \
        c = fmaf(ft_, c, it_ * gt_);                                                  \
        float th_ = fmaf(-2.0f,                                                       \
                         __builtin_amdgcn_rcpf(1.0f + __builtin_amdgcn_exp2f(c * TWO_L2E)), \
                         1.0f);                                                       \
        float u_ = ot_ * th_;                                                         \
        float sh_ = __builtin_amdgcn_sqrtf(h);                                        \
        float t1_ = fmaf(alpha, z * z, C0);                                           \
        h = fmaf(phi, h, fmaf(nag2 * z, sh_, t1_));                                   \
        float w_ = u_ * u_;                                                           \
        float pl_ = fmaf(w_, fmaf(w_, fmaf(w_, SPC4, SPC3), SPC2), SPC1);             \
        eta = fmaf(w_, pl_, fmaf(0.5f, u_, LN2));                                     \
        z = fmaf(-lam, eta, (YN)) * __builtin_amdgcn_rsqf(eta);                       \
    } while (0)

    const float4* __restrict__ y4 = reinterpret_cast<const float4*>(y);
    const float4* __restrict__ r4 = reinterpret_cast<const float4*>(rv);

    // ---------------- warm-up (no outputs) -------
    {
        int g = sstart >> 2;
        int g1 = g + 1; if (g1 > GMAX) g1 = GMAX;
        float4 yc = y4[g], rc = r4[g];
        float4 yn = y4[g1], rn = r4[g1];
        for (int ss = sstart; ss < send; ss += 4) {
            int g2 = g + 2; if (g2 > GMAX) g2 = GMAX;
            float4 ynn = y4[g2], rnn = r4[g2];
            STEP(yc.x, rc.x, yc.y);
            STEP(yc.y, rc.y, yc.z);
            STEP(yc.z, rc.z, yc.w);
            STEP(yc.w, rc.w, yn.x);
            g += 1;
            yc = yn; rc = rn;
            yn = ynn; rn = rnn;
        }
    }

    // ---------------- output phase: 64 steps, stage-then-step, one flush --
    {
        int g = send >> 2;
        float4 yc = y4[g], rc = r4[g];
        int g1 = g + 1; if (g1 > GMAX) g1 = GMAX;
        float4 yn = y4[g1], rn = r4[g1];
        const int lb0 = t * 65;

        for (int mq = 0; mq < 16; ++mq) {
            int g2 = g + 2; if (g2 > GMAX) g2 = GMAX;
            float4 ynn = y4[g2], rnn = r4[g2];
            const int jj = mq * 4;

            zs[lb0 + jj] = z;     hs[lb0 + jj] = h;
            STEP(yc.x, rc.x, yc.y);
            zs[lb0 + jj + 1] = z; hs[lb0 + jj + 1] = h;
            STEP(yc.y, rc.y, yc.z);
            zs[lb0 + jj + 2] = z; hs[lb0 + jj + 2] = h;
            STEP(yc.z, rc.z, yc.w);
            zs[lb0 + jj + 3] = z; hs[lb0 + jj + 3] = h;
            if (mq < 15) {
                STEP(yc.w, rc.w, yn.x);
            }
            g += 1;
            yc = yn; rc = rn;
            yn = ynn; rn = rnn;
        }

        __syncthreads();
        const long ob4 = (long)blockIdx.x * (CPB * (LBLK / 4));  // 1024 float4s/block
        float4* __restrict__ out4 = reinterpret_cast<float4*>(out);
#pragma unroll
        for (int ff = 0; ff < 16; ++ff) {
            int F = ff * CPB + t;
            int cc = F >> 4, qq = F & 15;
            int lb = cc * 65 + qq * 4;
            float4 zv = make_float4(zs[lb], zs[lb + 1], zs[lb + 2], zs[lb + 3]);
            float4 hv = make_float4(hs[lb], hs[lb + 1], hs[lb + 2], hs[lb + 3]);
            long o4 = ob4 + F;
            out4[o4] = zv;
            out4[(T_TOTAL >> 2) + o4] = hv;
        }
    }
#undef STEP
}

extern "C" void kernel_launch(void* const* d_in, const int* in_sizes, int n_in,
                              void* d_out, int out_size, void* d_ws, size_t ws_size,
                              hipStream_t stream) {
    const float* y  = (const float*)d_in[0];
    const float* rv = (const float*)d_in[1];
    const float* Wi = (const float*)d_in[2];
    const float* Ui = (const float*)d_in[3];
    const float* bi = (const float*)d_in[4];
    const float* Wf = (const float*)d_in[5];
    const float* Uf = (const float*)d_in[6];
    const float* bf = (const float*)d_in[7];
    const float* Wo = (const float*)d_in[8];
    const float* Uo = (const float*)d_in[9];
    const float* bo = (const float*)d_in[10];
    const float* Wc = (const float*)d_in[11];
    const float* Uc = (const float*)d_in[12];
    const float* bc = (const float*)d_in[13];
    const float* om = (const float*)d_in[14];
    const float* al = (const float*)d_in[15];
    const float* ph = (const float*)d_in[16];
    const float* la = (const float*)d_in[17];
    const float* ga = (const float*)d_in[18];
    float* out = (float*)d_out;
    double* ws = (double*)d_ws;

    var_reduce<<<VBLK, 256, 0, stream>>>(y, ws);
    scan_blocks<<<NBLK, CPB, 0, stream>>>(
        y, rv, Wi, Ui, bi, Wf, Uf, bf, Wo, Uo, bo, Wc, Uc, bc,
        om, al, ph, la, ga, ws, out);
}

// Round 7
// 167.916 us; speedup vs baseline: 3.7196x; 1.1518x over previous
//
#include <hip/hip_runtime.h>

#define T_TOTAL 4194304
#define LBLK 32                        // outputs per chain
#define WARM1 128                      // warm-up steps (multiple of 4)
#define NCHAIN (T_TOTAL / LBLK)        // 131072 chains
#define CPB 64                         // chains per block = 1 wave
#define NBLK (NCHAIN / CPB)            // 2048 blocks -> 8 waves/CU = 2/SIMD
#define VBLK 256                       // var_reduce blocks
#define GMAX ((T_TOTAL >> 2) - 1)

// ---------------- Kernel 1: variance partials (no atomics) ---------------
__global__ __launch_bounds__(256) void var_reduce(const float* __restrict__ y,
                                                  double* __restrict__ ws) {
    __shared__ double s_sum[4], s_sq[4];
    const float4* __restrict__ y4 = reinterpret_cast<const float4*>(y);
    int tid = blockIdx.x * 256 + threadIdx.x;
    const int nthr = VBLK * 256;
    double s = 0.0, q = 0.0;
    for (int i = tid; i < (T_TOTAL >> 2); i += nthr) {
        float4 v = y4[i];
        double a = v.x, b = v.y, c = v.z, d = v.w;
        s += (a + b) + (c + d);
        q += (a * a + b * b) + (c * c + d * d);
    }
    for (int off = 32; off > 0; off >>= 1) {
        s += __shfl_down(s, off, 64);
        q += __shfl_down(q, off, 64);
    }
    int lane = threadIdx.x & 63, wid = threadIdx.x >> 6;
    if (lane == 0) { s_sum[wid] = s; s_sq[wid] = q; }
    __syncthreads();
    if (threadIdx.x == 0) {
        ws[blockIdx.x] = s_sum[0] + s_sum[1] + s_sum[2] + s_sum[3];
        ws[VBLK + blockIdx.x] = s_sq[0] + s_sq[1] + s_sq[2] + s_sq[3];
    }
}

// ---------------- Kernel 2: blocked-in-time scan ----
__global__ __launch_bounds__(64, 2) void scan_blocks(
    const float* __restrict__ y, const float* __restrict__ rv,
    const float* __restrict__ Wi, const float* __restrict__ Ui, const float* __restrict__ bi,
    const float* __restrict__ Wf, const float* __restrict__ Uf, const float* __restrict__ bf,
    const float* __restrict__ Wo, const float* __restrict__ Uo, const float* __restrict__ bo,
    const float* __restrict__ Wc, const float* __restrict__ Uc, const float* __restrict__ bc,
    const float* __restrict__ p_omega, const float* __restrict__ p_alpha,
    const float* __restrict__ p_phi, const float* __restrict__ p_lam,
    const float* __restrict__ p_gam,
    const double* __restrict__ ws, float* __restrict__ out) {

    __shared__ float zs[CPB * 33];
    __shared__ float hs[CPB * 33];

    const int t = threadIdx.x;
    const int k = blockIdx.x * CPB + t;   // chain id; owns out[32k .. 32k+32)

    // ---- reduce variance partials (1 wave, no barrier needed) ----
    double s = ws[t] + ws[t + 64] + ws[t + 128] + ws[t + 192];
    double q = ws[VBLK + t] + ws[VBLK + t + 64] + ws[VBLK + t + 128] + ws[VBLK + t + 192];
    for (int off = 32; off > 0; off >>= 1) {
        s += __shfl_down(s, off, 64);
        q += __shfl_down(q, off, 64);
    }
    s = __shfl(s, 0, 64);
    q = __shfl(q, 0, 64);
    const float var = (float)((q - s * s / (double)T_TOTAL) / (double)T_TOTAL);

    const float L2E = 1.44269504088896340736f;
    const float TWO_L2E = 2.88539008177792681472f;
    const float LN2 = 0.69314718055994530942f;
    const float SPC1 = 0.125f;
    const float SPC2 = -5.2083333333e-3f;
    const float SPC3 = 3.4722222222e-4f;
    const float SPC4 = -2.6351897e-5f;

    const float nA_i = -L2E * (Wi[0] + Ui[0]);
    const float nBy_i = -L2E * Wi[1], nBr_i = -L2E * Wi[2], nBz_i = -L2E * Wi[3];
    const float nb_i = -L2E * bi[0];
    const float nA_f = -L2E * (Wf[0] + Uf[0]);
    const float nBy_f = -L2E * Wf[1], nBr_f = -L2E * Wf[2], nBz_f = -L2E * Wf[3];
    const float nb_f = -L2E * bf[0];
    const float nA_o = -L2E * (Wo[0] + Uo[0]);
    const float nBy_o = -L2E * Wo[1], nBr_o = -L2E * Wo[2], nBz_o = -L2E * Wo[3];
    const float nb_o = -L2E * bo[0];
    const float tA_c = TWO_L2E * (Wc[0] + Uc[0]);
    const float tBy_c = TWO_L2E * Wc[1], tBr_c = TWO_L2E * Wc[2], tBz_c = TWO_L2E * Wc[3];
    const float tb_c = TWO_L2E * bc[0];

    const float omega = p_omega[0], alpha = p_alpha[0], phi = p_phi[0];
    const float lam = p_lam[0], gam = p_gam[0];
    const float C0 = omega * (1.0f - phi) - alpha;
    const float nag2 = -2.0f * alpha * gam;

    int sstart = k * LBLK - WARM1;
    if (sstart < 0) sstart = 0;
    const int send = k * LBLK;

    // carry init: EXACT for chains with sstart==0 (k<=4); in-basin guess otherwise
    float eta = var, c = 0.0f, h = var;
    float z = fmaf(-lam, eta, y[sstart]) * __builtin_amdgcn_rsqf(eta);

#define STEP(YS, RS, YN)                                                              \
    do {                                                                              \
        float bi_ = fmaf(nBy_i, (YS), fmaf(nBr_i, (RS), nb_i));                       \
        float bf_ = fmaf(nBy_f, (YS), fmaf(nBr_f, (RS), nb_f));                       \
        float bo_ = fmaf(nBy_o, (YS), fmaf(nBr_o, (RS), nb_o));                       \
        float bc_ = fmaf(tBy_c, (YS), fmaf(tBr_c, (RS), tb_c));                       \
        float pi_ = fmaf(nA_i, eta, fmaf(nBz_i, z, bi_));                             \
        float pf_ = fmaf(nA_f, eta, fmaf(nBz_f, z, bf_));                             \
        float po_ = fmaf(nA_o, eta, fmaf(nBz_o, z, bo_));                             \
        float pc_ = fmaf(tA_c, eta, fmaf(tBz_c, z, bc_));                             \
        float it_ = __builtin_amdgcn_rcpf(1.0f + __builtin_amdgcn_exp2f(pi_));        \
        float ft_ = __builtin_amdgcn_rcpf(1.0f + __builtin_amdgcn_exp2f(pf_));        \
        float ot_ = __builtin_amdgcn_rcpf(1.0f + __builtin_amdgcn_exp2f(po_));        \
        float gt_ = fmaf(-2.0f, __builtin_amdgcn_rcpf(1.0f + __builtin_amdgcn_exp2f(pc_)), 1.0f); \
        c = fmaf(ft_, c, it_ * gt_);                                                  \
        float th_ = fmaf(-2.0f,                                                       \
                         __builtin_amdgcn_rcpf(1.0f + __builtin_amdgcn_exp2f(c * TWO_L2E)), \
                         1.0f);                                                       \
        float u_ = ot_ * th_;                                                         \
        float sh_ = __builtin_amdgcn_sqrtf(h);                                        \
        float t1_ = fmaf(alpha, z * z, C0);                                           \
        h = fmaf(phi, h, fmaf(nag2 * z, sh_, t1_));                                   \
        float w_ = u_ * u_;                                                           \
        float pl_ = fmaf(w_, fmaf(w_, fmaf(w_, SPC4, SPC3), SPC2), SPC1);             \
        eta = fmaf(w_, pl_, fmaf(0.5f, u_, LN2));                                     \
        z = fmaf(-lam, eta, (YN)) * __builtin_amdgcn_rsqf(eta);                       \
    } while (0)

    const float4* __restrict__ y4 = reinterpret_cast<const float4*>(y);
    const float4* __restrict__ r4 = reinterpret_cast<const float4*>(rv);

    // ---------------- warm-up (no outputs) -------
    {
        int g = sstart >> 2;
        int g1 = g + 1; if (g1 > GMAX) g1 = GMAX;
        float4 yc = y4[g], rc = r4[g];
        float4 yn = y4[g1], rn = r4[g1];
        for (int ss = sstart; ss < send; ss += 4) {
            int g2 = g + 2; if (g2 > GMAX) g2 = GMAX;
            float4 ynn = y4[g2], rnn = r4[g2];
            STEP(yc.x, rc.x, yc.y);
            STEP(yc.y, rc.y, yc.z);
            STEP(yc.z, rc.z, yc.w);
            STEP(yc.w, rc.w, yn.x);
            g += 1;
            yc = yn; rc = rn;
            yn = ynn; rn = rnn;
        }
    }

    // ---------------- output phase: 32 steps, stage-then-step, one flush --
    {
        int g = send >> 2;
        float4 yc = y4[g], rc = r4[g];
        int g1 = g + 1; if (g1 > GMAX) g1 = GMAX;
        float4 yn = y4[g1], rn = r4[g1];
        const int lb0 = t * 33;

        for (int mq = 0; mq < 8; ++mq) {
            int g2 = g + 2; if (g2 > GMAX) g2 = GMAX;
            float4 ynn = y4[g2], rnn = r4[g2];
            const int jj = mq * 4;

            zs[lb0 + jj] = z;     hs[lb0 + jj] = h;
            STEP(yc.x, rc.x, yc.y);
            zs[lb0 + jj + 1] = z; hs[lb0 + jj + 1] = h;
            STEP(yc.y, rc.y, yc.z);
            zs[lb0 + jj + 2] = z; hs[lb0 + jj + 2] = h;
            STEP(yc.z, rc.z, yc.w);
            zs[lb0 + jj + 3] = z; hs[lb0 + jj + 3] = h;
            if (mq < 7) {
                STEP(yc.w, rc.w, yn.x);
            }
            g += 1;
            yc = yn; rc = rn;
            yn = ynn; rn = rnn;
        }

        __syncthreads();
        const long ob4 = (long)blockIdx.x * (CPB * (LBLK / 4));  // 512 float4s/block
        float4* __restrict__ out4 = reinterpret_cast<float4*>(out);
#pragma unroll
        for (int ff = 0; ff < 8; ++ff) {
            int F = ff * CPB + t;
            int cc = F >> 3, qq = F & 7;
            int lb = cc * 33 + qq * 4;
            float4 zv = make_float4(zs[lb], zs[lb + 1], zs[lb + 2], zs[lb + 3]);
            float4 hv = make_float4(hs[lb], hs[lb + 1], hs[lb + 2], hs[lb + 3]);
            long o4 = ob4 + F;
            out4[o4] = zv;
            out4[(T_TOTAL >> 2) + o4] = hv;
        }
    }
#undef STEP
}

extern "C" void kernel_launch(void* const* d_in, const int* in_sizes, int n_in,
                              void* d_out, int out_size, void* d_ws, size_t ws_size,
                              hipStream_t stream) {
    const float* y  = (const float*)d_in[0];
    const float* rv = (const float*)d_in[1];
    const float* Wi = (const float*)d_in[2];
    const float* Ui = (const float*)d_in[3];
    const float* bi = (const float*)d_in[4];
    const float* Wf = (const float*)d_in[5];
    const float* Uf = (const float*)d_in[6];
    const float* bf = (const float*)d_in[7];
    const float* Wo = (const float*)d_in[8];
    const float* Uo = (const float*)d_in[9];
    const float* bo = (const float*)d_in[10];
    const float* Wc = (const float*)d_in[11];
    const float* Uc = (const float*)d_in[12];
    const float* bc = (const float*)d_in[13];
    const float* om = (const float*)d_in[14];
    const float* al = (const float*)d_in[15];
    const float* ph = (const float*)d_in[16];
    const float* la = (const float*)d_in[17];
    const float* ga = (const float*)d_in[18];
    float* out = (float*)d_out;
    double* ws = (double*)d_ws;

    var_reduce<<<VBLK, 256, 0, stream>>>(y, ws);
    scan_blocks<<<NBLK, CPB, 0, stream>>>(
        y, rv, Wi, Ui, bi, Wf, Uf, bf, Wo, Uo, bo, Wc, Uc, bc,
        om, al, ph, la, ga, ws, out);
}

// Round 8
// 150.202 us; speedup vs baseline: 4.1583x; 1.1179x over previous
//
#include <hip/hip_runtime.h>

#define T_TOTAL 4194304
#define LBLK 64                        // outputs per chain
#define WARM1 128                      // warm-up steps (multiple of 4)
#define NCHAIN (T_TOTAL / LBLK)        // 65536 chains
#define CPB 64                         // chains per block = 1 wave
#define NBLK (NCHAIN / CPB)            // 1024 blocks -> 1 wave/SIMD chip-wide
#define VBLK 256                       // var_reduce blocks
#define GMAX ((T_TOTAL >> 2) - 1)

// ---------------- Kernel 1: variance partials (no atomics) ---------------
__global__ __launch_bounds__(256) void var_reduce(const float* __restrict__ y,
                                                  double* __restrict__ ws) {
    __shared__ double s_sum[4], s_sq[4];
    const float4* __restrict__ y4 = reinterpret_cast<const float4*>(y);
    int tid = blockIdx.x * 256 + threadIdx.x;
    const int nthr = VBLK * 256;
    double s = 0.0, q = 0.0;
    for (int i = tid; i < (T_TOTAL >> 2); i += nthr) {
        float4 v = y4[i];
        double a = v.x, b = v.y, c = v.z, d = v.w;
        s += (a + b) + (c + d);
        q += (a * a + b * b) + (c * c + d * d);
    }
    for (int off = 32; off > 0; off >>= 1) {
        s += __shfl_down(s, off, 64);
        q += __shfl_down(q, off, 64);
    }
    int lane = threadIdx.x & 63, wid = threadIdx.x >> 6;
    if (lane == 0) { s_sum[wid] = s; s_sq[wid] = q; }
    __syncthreads();
    if (threadIdx.x == 0) {
        ws[blockIdx.x] = s_sum[0] + s_sum[1] + s_sum[2] + s_sum[3];
        ws[VBLK + blockIdx.x] = s_sq[0] + s_sq[1] + s_sq[2] + s_sq[3];
    }
}

// ---------------- Kernel 2: blocked-in-time scan ----
__global__ __launch_bounds__(64) void scan_blocks(
    const float* __restrict__ y, const float* __restrict__ rv,
    const float* __restrict__ Wi, const float* __restrict__ Ui, const float* __restrict__ bi,
    const float* __restrict__ Wf, const float* __restrict__ Uf, const float* __restrict__ bf,
    const float* __restrict__ Wo, const float* __restrict__ Uo, const float* __restrict__ bo,
    const float* __restrict__ Wc, const float* __restrict__ Uc, const float* __restrict__ bc,
    const float* __restrict__ p_omega, const float* __restrict__ p_alpha,
    const float* __restrict__ p_phi, const float* __restrict__ p_lam,
    const float* __restrict__ p_gam,
    const double* __restrict__ ws, float* __restrict__ out) {

    __shared__ float zs[CPB * 65];
    __shared__ float hs[CPB * 65];

    const int t = threadIdx.x;
    const int k = blockIdx.x * CPB + t;   // chain id; owns out[64k .. 64k+64)

    // ---- reduce variance partials (1 wave, no barrier needed) ----
    double s = ws[t] + ws[t + 64] + ws[t + 128] + ws[t + 192];
    double q = ws[VBLK + t] + ws[VBLK + t + 64] + ws[VBLK + t + 128] + ws[VBLK + t + 192];
    for (int off = 32; off > 0; off >>= 1) {
        s += __shfl_down(s, off, 64);
        q += __shfl_down(q, off, 64);
    }
    s = __shfl(s, 0, 64);
    q = __shfl(q, 0, 64);
    const float var = (float)((q - s * s / (double)T_TOTAL) / (double)T_TOTAL);

    const float L2E = 1.44269504088896340736f;
    const float TWO_L2E = 2.88539008177792681472f;
    const float LN2 = 0.69314718055994530942f;
    const float SPC1 = 0.125f;
    const float SPC2 = -5.2083333333e-3f;
    const float SPC3 = 3.4722222222e-4f;
    const float SPC4 = -2.6351897e-5f;

    const float nA_i = -L2E * (Wi[0] + Ui[0]);
    const float nBy_i = -L2E * Wi[1], nBr_i = -L2E * Wi[2], nBz_i = -L2E * Wi[3];
    const float nb_i = -L2E * bi[0];
    const float nA_f = -L2E * (Wf[0] + Uf[0]);
    const float nBy_f = -L2E * Wf[1], nBr_f = -L2E * Wf[2], nBz_f = -L2E * Wf[3];
    const float nb_f = -L2E * bf[0];
    const float nA_o = -L2E * (Wo[0] + Uo[0]);
    const float nBy_o = -L2E * Wo[1], nBr_o = -L2E * Wo[2], nBz_o = -L2E * Wo[3];
    const float nb_o = -L2E * bo[0];
    const float tA_c = TWO_L2E * (Wc[0] + Uc[0]);
    const float tBy_c = TWO_L2E * Wc[1], tBr_c = TWO_L2E * Wc[2], tBz_c = TWO_L2E * Wc[3];
    const float tb_c = TWO_L2E * bc[0];

    const float omega = p_omega[0], alpha = p_alpha[0], phi = p_phi[0];
    const float lam = p_lam[0], gam = p_gam[0];
    const float C0 = omega * (1.0f - phi) - alpha;
    const float nag2 = -2.0f * alpha * gam;

    int sstart = k * LBLK - WARM1;
    if (sstart < 0) sstart = 0;
    const int send = k * LBLK;

    // carry init: EXACT for chains with sstart==0 (k<=2); in-basin guess otherwise
    float eta = var, c = 0.0f, h = var;
    float z = fmaf(-lam, eta, y[sstart]) * __builtin_amdgcn_rsqf(eta);

#define STEP(YS, RS, YN)                                                              \
    do {                                                                              \
        float bi_ = fmaf(nBy_i, (YS), fmaf(nBr_i, (RS), nb_i));                       \
        float bf_ = fmaf(nBy_f, (YS), fmaf(nBr_f, (RS), nb_f));                       \
        float bo_ = fmaf(nBy_o, (YS), fmaf(nBr_o, (RS), nb_o));                       \
        float bc_ = fmaf(tBy_c, (YS), fmaf(tBr_c, (RS), tb_c));                       \
        float pi_ = fmaf(nA_i, eta, fmaf(nBz_i, z, bi_));                             \
        float pf_ = fmaf(nA_f, eta, fmaf(nBz_f, z, bf_));                             \
        float po_ = fmaf(nA_o, eta, fmaf(nBz_o, z, bo_));                             \
        float pc_ = fmaf(tA_c, eta, fmaf(tBz_c, z, bc_));                             \
        float it_ = __builtin_amdgcn_rcpf(1.0f + __builtin_amdgcn_exp2f(pi_));        \
        float ft_ = __builtin_amdgcn_rcpf(1.0f + __builtin_amdgcn_exp2f(pf_));        \
        float ot_ = __builtin_amdgcn_rcpf(1.0f + __builtin_amdgcn_exp2f(po_));        \
        float gt_ = fmaf(-2.0f, __builtin_amdgcn_rcpf(1.0f + __builtin_amdgcn_exp2f(pc_)), 1.0f); \
        c = fmaf(ft_, c, it_ * gt_);                                                  \
        float th_ = fmaf(-2.0f,                                                       \
                         __builtin_amdgcn_rcpf(1.0f + __builtin_amdgcn_exp2f(c * TWO_L2E)), \
                         1.0f);                                                       \
        float u_ = ot_ * th_;                                                         \
        float sh_ = __builtin_amdgcn_sqrtf(h);                                        \
        float t1_ = fmaf(alpha, z * z, C0);                                           \
        h = fmaf(phi, h, fmaf(nag2 * z, sh_, t1_));                                   \
        float w_ = u_ * u_;                                                           \
        float pl_ = fmaf(w_, fmaf(w_, fmaf(w_, SPC4, SPC3), SPC2), SPC1);             \
        eta = fmaf(w_, pl_, fmaf(0.5f, u_, LN2));                                     \
        z = fmaf(-lam, eta, (YN)) * __builtin_amdgcn_rsqf(eta);                       \
    } while (0)

    const float4* __restrict__ y4 = reinterpret_cast<const float4*>(y);
    const float4* __restrict__ r4 = reinterpret_cast<const float4*>(rv);

    // ---------------- warm-up (no outputs) -------
    {
        int g = sstart >> 2;
        int g1 = g + 1; if (g1 > GMAX) g1 = GMAX;
        float4 yc = y4[g], rc = r4[g];
        float4 yn = y4[g1], rn = r4[g1];
        for (int ss = sstart; ss < send; ss += 4) {
            int g2 = g + 2; if (g2 > GMAX) g2 = GMAX;
            float4 ynn = y4[g2], rnn = r4[g2];
            STEP(yc.x, rc.x, yc.y);
            STEP(yc.y, rc.y, yc.z);
            STEP(yc.z, rc.z, yc.w);
            STEP(yc.w, rc.w, yn.x);
            g += 1;
            yc = yn; rc = rn;
            yn = ynn; rn = rnn;
        }
    }

    // ---------------- output phase: 64 steps, stage-then-step, one flush --
    {
        int g = send >> 2;
        float4 yc = y4[g], rc = r4[g];
        int g1 = g + 1; if (g1 > GMAX) g1 = GMAX;
        float4 yn = y4[g1], rn = r4[g1];
        const int lb0 = t * 65;

        for (int mq = 0; mq < 16; ++mq) {
            int g2 = g + 2; if (g2 > GMAX) g2 = GMAX;
            float4 ynn = y4[g2], rnn = r4[g2];
            const int jj = mq * 4;

            zs[lb0 + jj] = z;     hs[lb0 + jj] = h;
            STEP(yc.x, rc.x, yc.y);
            zs[lb0 + jj + 1] = z; hs[lb0 + jj + 1] = h;
            STEP(yc.y, rc.y, yc.z);
            zs[lb0 + jj + 2] = z; hs[lb0 + jj + 2] = h;
            STEP(yc.z, rc.z, yc.w);
            zs[lb0 + jj + 3] = z; hs[lb0 + jj + 3] = h;
            if (mq < 15) {
                STEP(yc.w, rc.w, yn.x);
            }
            g += 1;
            yc = yn; rc = rn;
            yn = ynn; rn = rnn;
        }

        __syncthreads();
        const long ob4 = (long)blockIdx.x * (CPB * (LBLK / 4));  // 1024 float4s/block
        float4* __restrict__ out4 = reinterpret_cast<float4*>(out);
#pragma unroll
        for (int ff = 0; ff < 16; ++ff) {
            int F = ff * CPB + t;
            int cc = F >> 4, qq = F & 15;
            int lb = cc * 65 + qq * 4;
            float4 zv = make_float4(zs[lb], zs[lb + 1], zs[lb + 2], zs[lb + 3]);
            float4 hv = make_float4(hs[lb], hs[lb + 1], hs[lb + 2], hs[lb + 3]);
            long o4 = ob4 + F;
            out4[o4] = zv;
            out4[(T_TOTAL >> 2) + o4] = hv;
        }
    }
#undef STEP
}

extern "C" void kernel_launch(void* const* d_in, const int* in_sizes, int n_in,
                              void* d_out, int out_size, void* d_ws, size_t ws_size,
                              hipStream_t stream) {
    const float* y  = (const float*)d_in[0];
    const float* rv = (const float*)d_in[1];
    const float* Wi = (const float*)d_in[2];
    const float* Ui = (const float*)d_in[3];
    const float* bi = (const float*)d_in[4];
    const float* Wf = (const float*)d_in[5];
    const float* Uf = (const float*)d_in[6];
    const float* bf = (const float*)d_in[7];
    const float* Wo = (const float*)d_in[8];
    const float* Uo = (const float*)d_in[9];
    const float* bo = (const float*)d_in[10];
    const float* Wc = (const float*)d_in[11];
    const float* Uc = (const float*)d_in[12];
    const float* bc = (const float*)d_in[13];
    const float* om = (const float*)d_in[14];
    const float* al = (const float*)d_in[15];
    const float* ph = (const float*)d_in[16];
    const float* la = (const float*)d_in[17];
    const float* ga = (const float*)d_in[18];
    float* out = (float*)d_out;
    double* ws = (double*)d_ws;

    var_reduce<<<VBLK, 256, 0, stream>>>(y, ws);
    scan_blocks<<<NBLK, CPB, 0, stream>>>(
        y, rv, Wi, Ui, bi, Wf, Uf, bf, Wo, Uo, bo, Wc, Uc, bc,
        om, al, ph, la, ga, ws, out);
}